// Round 1
// baseline (398.671 us; speedup 1.0000x reference)
//
#include <hip/hip_runtime.h>
#include <hip/hip_bf16.h>

typedef short bf16x8 __attribute__((ext_vector_type(8)));
typedef float f32x16 __attribute__((ext_vector_type(16)));
typedef float f32x4v __attribute__((ext_vector_type(4)));

#define GN 8192
#define GD 128
#define KSPLIT 8

// ws layout:
// [0, 32768)              : s (fp32, 8192) = rsqrt(rowsum)
// [32768, +2097152)       : yp bf16: 128 tiles x 16384 B, each tile =
//                           B-operand [col 0..127][kk 0..63] with byte
//                           offset XOR-swizzled by ((col&7)<<4)  (2 MB)
// [2129920, +134217728)   : adj_bf16 row-major, rows pre-scaled by s_i (128 MB)
// [136347648, +33554432)  : partials fp32 [8][8192][128]  (32 MB)

// Pass 1: rowsum -> s_i, and rewrite row as bf16 * s_i.  (unchanged)
__global__ __launch_bounds__(256) void k_rowcvt(const float* __restrict__ adj,
                                                float* __restrict__ s,
                                                __hip_bfloat16* __restrict__ adjb) {
  const int row = blockIdx.x;
  const int t = threadIdx.x;
  const f32x4v* p = (const f32x4v*)(adj + (size_t)row * GN);
  f32x4v v[8];
  float acc = 0.f;
#pragma unroll
  for (int i = 0; i < 8; ++i) {
    v[i] = __builtin_nontemporal_load(p + t + i * 256);
    acc += (v[i].x + v[i].y) + (v[i].z + v[i].w);
  }
#pragma unroll
  for (int off = 32; off > 0; off >>= 1) acc += __shfl_down(acc, off, 64);
  __shared__ float red[4];
  __shared__ float sbc;
  if ((t & 63) == 0) red[t >> 6] = acc;
  __syncthreads();
  if (t == 0) {
    float tot = (red[0] + red[1]) + (red[2] + red[3]);
    float sc = (tot > 0.f) ? rsqrtf(tot) : 0.f;
    sbc = sc;
    s[row] = sc;
  }
  __syncthreads();
  const float sc = sbc;
  __hip_bfloat16* orow = adjb + (size_t)row * GN;
#pragma unroll
  for (int i = 0; i < 8; ++i) {
    __hip_bfloat16 hb[4];
    hb[0] = __float2bfloat16(v[i].x * sc);
    hb[1] = __float2bfloat16(v[i].y * sc);
    hb[2] = __float2bfloat16(v[i].z * sc);
    hb[3] = __float2bfloat16(v[i].w * sc);
    *(uint2*)(orow + (size_t)(t + i * 256) * 4) = *(uint2*)hb;
  }
}

// y = (S x) @ W^T, packed into XOR-swizzled B-tiles so k_gemm can stage them
// with LINEAR global_load_lds and ds_read with the same XOR (bank-spread).
__global__ __launch_bounds__(256) void k_packy(const float* __restrict__ x,
                                               const float* __restrict__ s,
                                               const float* __restrict__ W,
                                               __hip_bfloat16* __restrict__ yp) {
  __shared__ __align__(16) __hip_bfloat16 Xs[64 * 136];
  __shared__ __align__(16) __hip_bfloat16 Ws[128 * 136];
  __shared__ __align__(16) __hip_bfloat16 Yp[128 * 64];
  __shared__ float sv[64];
  const int kb = blockIdx.x;
  const int t = threadIdx.x;
  if (t < 64) sv[t] = s[kb * 64 + t];
  __syncthreads();
  const float4* xp = (const float4*)(x + (size_t)kb * 64 * GD);
#pragma unroll
  for (int j = 0; j < 8; ++j) {
    int i = t + j * 256;
    int r = i >> 5, c4 = i & 31;
    float4 v = xp[i];
    float sc = sv[r];
    __hip_bfloat16 hb[4];
    hb[0] = __float2bfloat16(v.x * sc);
    hb[1] = __float2bfloat16(v.y * sc);
    hb[2] = __float2bfloat16(v.z * sc);
    hb[3] = __float2bfloat16(v.w * sc);
    *(uint2*)(Xs + r * 136 + c4 * 4) = *(uint2*)hb;
  }
#pragma unroll
  for (int j = 0; j < 16; ++j) {
    int i = t + j * 256;
    int o = i >> 5, k4 = i & 31;
    float4 w = *(const float4*)(W + (size_t)o * GD + k4 * 4);
    __hip_bfloat16 hb[4];
    hb[0] = __float2bfloat16(w.x);
    hb[1] = __float2bfloat16(w.y);
    hb[2] = __float2bfloat16(w.z);
    hb[3] = __float2bfloat16(w.w);
    *(uint2*)(Ws + o * 136 + k4 * 4) = *(uint2*)hb;
  }
  __syncthreads();
  const int lane = t & 63;
  const int wave = t >> 6;
  const int mtile = wave & 1;
  const int n0 = (wave >> 1) * 2;
  const int koff = (lane >> 5) * 8;
  const int arow = mtile * 32 + (lane & 31);
  f32x16 acc0, acc1;
#pragma unroll
  for (int i = 0; i < 16; ++i) { acc0[i] = 0.f; acc1[i] = 0.f; }
#pragma unroll
  for (int kk = 0; kk < 128; kk += 16) {
    bf16x8 af = *(const bf16x8*)(Xs + arow * 136 + kk + koff);
    bf16x8 b0 = *(const bf16x8*)(Ws + (n0 * 32 + (lane & 31)) * 136 + kk + koff);
    bf16x8 b1 = *(const bf16x8*)(Ws + ((n0 + 1) * 32 + (lane & 31)) * 136 + kk + koff);
    acc0 = __builtin_amdgcn_mfma_f32_32x32x16_bf16(af, b0, acc0, 0, 0, 0);
    acc1 = __builtin_amdgcn_mfma_f32_32x32x16_bf16(af, b1, acc1, 0, 0, 0);
  }
#pragma unroll
  for (int reg = 0; reg < 16; ++reg) {
    int kkl = mtile * 32 + (reg & 3) + 8 * (reg >> 2) + 4 * (lane >> 5);
    int c0 = n0 * 32 + (lane & 31);
    int xr = (c0 & 7) << 4;  // (c0+32)&7 == c0&7
    *(__hip_bfloat16*)((char*)Yp + ((c0 * 128 + kkl * 2) ^ xr)) = __float2bfloat16(acc0[reg]);
    *(__hip_bfloat16*)((char*)Yp + (((c0 + 32) * 128 + kkl * 2) ^ xr)) = __float2bfloat16(acc1[reg]);
  }
  __syncthreads();
  const uint4* srcv = (const uint4*)Yp;
  uint4* dstv = (uint4*)((char*)yp + (size_t)kb * 16384);
  for (int i = t; i < 1024; i += 256) dstv[i] = srcv[i];
}

// Main GEMM: part[ks] = adjb[:, slice] @ y[slice, :]
// Double-buffered LDS, ONE barrier per K-step, all staging via
// global_load_lds (A source pre-swizzled per-lane so the linear LDS write
// yields the XOR-swizzled layout; B pre-swizzled at pack time).
__global__ __launch_bounds__(256, 2) void k_gemm(const __hip_bfloat16* __restrict__ adjb,
                                                 const __hip_bfloat16* __restrict__ yp,
                                                 float* __restrict__ part) {
  __shared__ __align__(16) __hip_bfloat16 Asm[2][8192];  // [row 0..127][64] swizzled
  __shared__ __align__(16) __hip_bfloat16 Bsm[2][8192];  // [col 0..127][64] swizzled
  const int mb = blockIdx.x;   // 0..63  (128-row tile)
  const int ks = blockIdx.y;   // 0..7   (K split, 1024 each)
  const int t = threadIdx.x;
  const int lane = t & 63;
  const int wave = t >> 6;
  const int wm = wave >> 1, wn = wave & 1;
  const int l31 = lane & 31;
  const int koff = (lane >> 5) * 8;
  const int bxor = (l31 & 7) << 4;
  const int cid0 = wave * 4;   // this wave's 4 chunks (of 16) per tile

  f32x16 acc00, acc01, acc10, acc11;
#pragma unroll
  for (int i = 0; i < 16; ++i) {
    acc00[i] = 0.f; acc01[i] = 0.f; acc10[i] = 0.f; acc11[i] = 0.f;
  }

  // A staging: chunk c covers rows [c*8, c*8+8); lane l -> row c*8 + (l>>3),
  // 16B granule (l&7). Linear LDS dest => pre-swizzle the GLOBAL source
  // granule: col16' = (l&7) ^ ((l>>3)&7). Each instr fetches 8 full 128B rows.
  const int arow0 = cid0 * 8 + (lane >> 3);
  const int acol = ((lane & 7) ^ ((lane >> 3) & 7)) * 8;  // elements
  const __hip_bfloat16* aSrc0 = adjb + (size_t)(mb * 128 + arow0) * GN + ks * 1024 + acol;
  const char* bSrc0 = (const char*)yp + (size_t)(ks * 16) * 16384 + cid0 * 1024 + lane * 16;

#define STAGE(dbuf, kt_) do {                                                              \
    const __hip_bfloat16* as_ = aSrc0 + (kt_) * 64;                                        \
    const char* bs_ = bSrc0 + (size_t)(kt_) * 16384;                                       \
    _Pragma("unroll")                                                                      \
    for (int i_ = 0; i_ < 4; ++i_) {                                                       \
      __builtin_amdgcn_global_load_lds(                                                    \
          (const __attribute__((address_space(1))) unsigned int*)(as_ + (size_t)i_ * 8 * GN), \
          (__attribute__((address_space(3))) unsigned int*)(&Asm[dbuf][(cid0 + i_) * 512]),   \
          16, 0, 0);                                                                       \
      __builtin_amdgcn_global_load_lds(                                                    \
          (const __attribute__((address_space(1))) unsigned int*)(bs_ + i_ * 1024),        \
          (__attribute__((address_space(3))) unsigned int*)((char*)Bsm[dbuf] + (cid0 + i_) * 1024), \
          16, 0, 0);                                                                       \
    }                                                                                      \
  } while (0)

  STAGE(0, 0);
  __syncthreads();  // compiler-inserted vmcnt(0) drain makes buf0 ready

  const int aoff = (wm * 64 + l31) * 128;  // byte row base; (row&7)==(l31&7)
  const int boff = (wn * 64 + l31) * 128;

  for (int kt = 0; kt < 16; ++kt) {
    const int cur = kt & 1;
    if (kt < 15) STAGE(cur ^ 1, kt + 1);  // issue next tile; overlaps MFMA below
    const char* Ab = (const char*)Asm[cur] + aoff;
    const char* Bb = (const char*)Bsm[cur] + boff;
#pragma unroll
    for (int kk = 0; kk < 64; kk += 16) {
      const int off = ((kk + koff) * 2) ^ bxor;  // swizzled 16B granule
      bf16x8 a0 = *(const bf16x8*)(Ab + off);
      bf16x8 a1 = *(const bf16x8*)(Ab + 4096 + off);
      bf16x8 b0 = *(const bf16x8*)(Bb + off);
      bf16x8 b1 = *(const bf16x8*)(Bb + 4096 + off);
      acc00 = __builtin_amdgcn_mfma_f32_32x32x16_bf16(a0, b0, acc00, 0, 0, 0);
      acc01 = __builtin_amdgcn_mfma_f32_32x32x16_bf16(a0, b1, acc01, 0, 0, 0);
      acc10 = __builtin_amdgcn_mfma_f32_32x32x16_bf16(a1, b0, acc10, 0, 0, 0);
      acc11 = __builtin_amdgcn_mfma_f32_32x32x16_bf16(a1, b1, acc11, 0, 0, 0);
    }
    if (kt < 15) __syncthreads();  // single barrier per K-step: drains next stage
  }
#undef STAGE

  float* pb = part + (size_t)ks * GN * GD + (size_t)(mb * 128) * GD;
#pragma unroll
  for (int reg = 0; reg < 16; ++reg) {
    int r0 = wm * 64 + (reg & 3) + 8 * (reg >> 2) + 4 * (lane >> 5);
    int c0 = wn * 64 + l31;
    pb[(size_t)r0 * GD + c0] = acc00[reg];
    pb[(size_t)r0 * GD + c0 + 32] = acc01[reg];
    pb[(size_t)(r0 + 32) * GD + c0] = acc10[reg];
    pb[(size_t)(r0 + 32) * GD + c0 + 32] = acc11[reg];
  }
}

// out = sum_ks part[ks] + bias  (unchanged)
__global__ __launch_bounds__(256) void k_red(const float* __restrict__ part,
                                             const float* __restrict__ b,
                                             float* __restrict__ out) {
  __shared__ float4 bs4[32];
  const int t = threadIdx.x;
  if (t < 32) bs4[t] = ((const float4*)b)[t];
  __syncthreads();
  const int row0 = blockIdx.x * 32;
#pragma unroll
  for (int j = 0; j < 4; ++j) {
    int i = t + j * 256;               // 1024 float4 = 32 rows x 32
    int r = i >> 5, c4 = i & 31;
    size_t idx = (size_t)(row0 + r) * GD + c4 * 4;
    float4 a = bs4[c4];
#pragma unroll
    for (int ksl = 0; ksl < KSPLIT; ++ksl) {
      float4 p = *(const float4*)(part + idx + (size_t)ksl * GN * GD);
      a.x += p.x; a.y += p.y; a.z += p.z; a.w += p.w;
    }
    *(float4*)(out + idx) = a;
  }
}

extern "C" void kernel_launch(void* const* d_in, const int* in_sizes, int n_in,
                              void* d_out, int out_size, void* d_ws, size_t ws_size,
                              hipStream_t stream) {
  const float* x   = (const float*)d_in[0];
  const float* adj = (const float*)d_in[1];
  const float* W   = (const float*)d_in[2];
  const float* b   = (const float*)d_in[3];
  float* out = (float*)d_out;

  float* s = (float*)d_ws;
  __hip_bfloat16* yp   = (__hip_bfloat16*)((char*)d_ws + 32768);
  __hip_bfloat16* adjb = (__hip_bfloat16*)((char*)d_ws + 2129920);
  float* part = (float*)((char*)d_ws + 136347648);

  k_rowcvt<<<8192, 256, 0, stream>>>(adj, s, adjb);
  k_packy<<<128, 256, 0, stream>>>(x, s, W, yp);
  k_gemm<<<dim3(64, KSPLIT), 256, 0, stream>>>(adjb, yp, part);
  k_red<<<256, 256, 0, stream>>>(part, b, out);
}